// Round 13
// baseline (414.641 us; speedup 1.0000x reference)
//
#include <hip/hip_runtime.h>
#include <hip/hip_bf16.h>

// RGCN encoder: N=100000, E=128, R=9, L=3, NE=640000. Only the LAST layer
// matters (reference resets hidden=embeddings each layer).
//   out[n] = sum_{e:dst=n}(W_t h[src]+b_t) + sum_{e:src=n}(W_{t+9} h[dst]+b_{t+9})
// AGGREGATE-FIRST (linearity): out[d] = sum_t W_t * M_t[d] + deg_t(d)*b_t.
// Round-13: r12 processed one 256B row per whole-wave step (readlane
// broadcast -> vmcnt(0) drain each batch). Now: node w*4+g belongs to
// 16-lane group g (8 ch/lane via short8); each group streams its own
// segment with a predicated 4-deep loop -> 16 rows in flight per wave,
// no readlane, no full drains. Same-(node,type) RMW collisions exist only
// within a group -> ordered by the in-order LDS pipe (r12-validated).
// CSR (node,type)-sorted, MFMA (swapped operands), deg*b epilogue: as r12.

#define E_DIM 128
#define R_REL 9
#define TN 16        // nodes per fused block
#define MT_P 1156    // Mt pitch in ushorts
#define SCB 1024     // elements per scan block
#define NSLICE 96    // edge slices per octant in count/fill

typedef __attribute__((ext_vector_type(8))) short short8v;
typedef __attribute__((ext_vector_type(4))) float f32x4;

static __device__ __forceinline__ unsigned short f2bf(float f) {
    union { float f; unsigned u; } v; v.f = f;
    unsigned u = v.u;
    return (unsigned short)((u + 0x7FFFu + ((u >> 16) & 1u)) >> 16);
}
static __device__ __forceinline__ float bf2f(unsigned short h) {
    union { unsigned u; float f; } v; v.u = ((unsigned)h) << 16;
    return v.f;
}

// ---------- fast path ----------

// Combined prep: blocks 0..17 swizzle W into MFMA fragment order; blocks 18..
// convert H fp32 -> bf16.
__global__ __launch_bounds__(256) void prep(
    const float* __restrict__ H, const float* __restrict__ W18,
    unsigned short* __restrict__ Hbf, unsigned short* __restrict__ Wt,
    long total8)
{
    const int tid = threadIdx.x;
    if (blockIdx.x < 18) {
        const int rel = blockIdx.x;
        const float* __restrict__ Wr = W18 + (size_t)rel * E_DIM * E_DIM;
#pragma unroll
        for (int k = 0; k < 8; k++) {
            int f = tid + k * 256;            // 0..2047
            int lane = f & 63;
            int c = (f >> 6) & 1;
            int s = (f >> 7) & 3;
            int w = (f >> 9) & 3;
            int col = w * 32 + c * 16 + (lane & 15);
            int kb = s * 32 + (lane >> 4) * 8;
            short8v v;
#pragma unroll
            for (int j = 0; j < 8; j++)
                v[j] = (short)f2bf(Wr[(size_t)(kb + j) * E_DIM + col]);
            *(short8v*)(Wt + ((size_t)((((rel * 4 + w) * 4 + s) * 2 + c) * 64 + lane)) * 8) = v;
        }
    } else {
        long i = (long)(blockIdx.x - 18) * 256 + tid;
        if (i >= total8) return;
        const float4* src = (const float4*)(H + i * 8);
        float4 a = src[0], b = src[1];
        short8v o;
        o[0] = (short)f2bf(a.x); o[1] = (short)f2bf(a.y);
        o[2] = (short)f2bf(a.z); o[3] = (short)f2bf(a.w);
        o[4] = (short)f2bf(b.x); o[5] = (short)f2bf(b.y);
        o[6] = (short)f2bf(b.z); o[7] = (short)f2bf(b.w);
        *(short8v*)(Hbf + i * 8) = o;
    }
}

// CSR over n3 = 2*Nn*9 (node,dir,type) segments; key = seg*9+t, seg = d (fwd)
// or Nn+s (bwd). Octant-partitioned by node: counter window L2-local.
__global__ __launch_bounds__(256) void k_count8(
    const int* __restrict__ esrc, const int* __restrict__ edst,
    const int* __restrict__ etype, int* __restrict__ cnt, int ne, int Nn)
{
    const int oct = blockIdx.x & 7;
    const int slice = blockIdx.x >> 3;
    const int lo = (int)(((long long)oct * Nn) >> 3);
    const int hi = (int)(((long long)(oct + 1) * Nn) >> 3);
    for (int e = slice * 256 + threadIdx.x; e < ne; e += NSLICE * 256) {
        int t = etype[e], s = esrc[e], d = edst[e];
        if (d >= lo && d < hi) atomicAdd(&cnt[d * R_REL + t], 1);
        if (s >= lo && s < hi) atomicAdd(&cnt[(Nn + s) * R_REL + t], 1);
    }
}

// Hierarchical scan, 3 kernels (r5-validated).
__global__ __launch_bounds__(256) void k_scan_part(
    const int* __restrict__ cnt, int* __restrict__ loc,
    int* __restrict__ bsum, int n2)
{
    __shared__ int sh[256];
    const int tid = threadIdx.x;
    const int i0 = blockIdx.x * SCB + tid * 4;
    int v0 = 0, v1 = 0, v2 = 0, v3 = 0;
    if (i0 + 3 < n2) {
        int4 v = *(const int4*)(cnt + i0);
        v0 = v.x; v1 = v.y; v2 = v.z; v3 = v.w;
    } else {
        if (i0 + 0 < n2) v0 = cnt[i0 + 0];
        if (i0 + 1 < n2) v1 = cnt[i0 + 1];
        if (i0 + 2 < n2) v2 = cnt[i0 + 2];
        if (i0 + 3 < n2) v3 = cnt[i0 + 3];
    }
    int t = v0 + v1 + v2 + v3;
    sh[tid] = t;
    __syncthreads();
    for (int o = 1; o < 256; o <<= 1) {
        int x = (tid >= o) ? sh[tid - o] : 0;
        __syncthreads();
        sh[tid] += x;
        __syncthreads();
    }
    int excl = sh[tid] - t;
    if (tid == 255) bsum[blockIdx.x] = sh[255];
    int p0 = excl, p1 = p0 + v0, p2 = p1 + v1, p3 = p2 + v2;
    if (i0 + 3 < n2) {
        *(int4*)(loc + i0) = make_int4(p0, p1, p2, p3);
    } else {
        if (i0 + 0 < n2) loc[i0 + 0] = p0;
        if (i0 + 1 < n2) loc[i0 + 1] = p1;
        if (i0 + 2 < n2) loc[i0 + 2] = p2;
        if (i0 + 3 < n2) loc[i0 + 3] = p3;
    }
}

__global__ __launch_bounds__(256) void k_scan_mid(int* __restrict__ bsum, int nb)
{
    __shared__ int sh[256];
    __shared__ int carry;
    const int tid = threadIdx.x;
    if (tid == 0) carry = 0;
    __syncthreads();
    for (int base = 0; base < nb; base += 256) {
        int i = base + tid;
        int v = (i < nb) ? bsum[i] : 0;
        sh[tid] = v;
        __syncthreads();
        for (int o = 1; o < 256; o <<= 1) {
            int x = (tid >= o) ? sh[tid - o] : 0;
            __syncthreads();
            sh[tid] += x;
            __syncthreads();
        }
        int excl = sh[tid] - v + carry;
        int total = sh[255];
        if (i < nb) bsum[i] = excl;
        __syncthreads();
        if (tid == 0) carry += total;
        __syncthreads();
    }
}

__global__ __launch_bounds__(256) void k_scan_apply(
    const int* __restrict__ loc, const int* __restrict__ bsum,
    int* __restrict__ off, int* __restrict__ cursor, int n2)
{
    const int add = bsum[blockIdx.x];
    const int i0 = blockIdx.x * SCB + threadIdx.x * 4;
    if (i0 + 3 < n2) {
        int4 v = *(const int4*)(loc + i0);
        v.x += add; v.y += add; v.z += add; v.w += add;
        *(int4*)(off + i0) = v;
        *(int4*)(cursor + i0) = v;
    } else {
#pragma unroll
        for (int j = 0; j < 4; j++)
            if (i0 + j < n2) {
                int v = loc[i0 + j] + add;
                off[i0 + j] = v;
                cursor[i0 + j] = v;
            }
    }
}

// rec = (t<<20) | otherNode, via (node,t) cursor -> type-grouped per node.
__global__ __launch_bounds__(256) void k_fill8(
    const int* __restrict__ esrc, const int* __restrict__ edst,
    const int* __restrict__ etype, int* __restrict__ cursor,
    unsigned* __restrict__ rec, int ne, int Nn)
{
    const int oct = blockIdx.x & 7;
    const int slice = blockIdx.x >> 3;
    const int lo = (int)(((long long)oct * Nn) >> 3);
    const int hi = (int)(((long long)(oct + 1) * Nn) >> 3);
    for (int e = slice * 256 + threadIdx.x; e < ne; e += NSLICE * 256) {
        int t = etype[e], s = esrc[e], d = edst[e];
        if (d >= lo && d < hi) {
            int p = atomicAdd(&cursor[d * R_REL + t], 1);
            rec[p] = ((unsigned)t << 20) | (unsigned)s;   // fwd msg into d
        }
        if (s >= lo && s < hi) {
            int p2 = atomicAdd(&cursor[(Nn + s) * R_REL + t], 1);
            rec[p2] = ((unsigned)t << 20) | (unsigned)d;  // bwd msg into s
        }
    }
}

// Fused aggregate+GEMM. Block = 16 nodes, 4 waves, 4 blocks/CU. Per dir:
//  - wave zeroes its 4 Mt rows (wave-private)
//  - bounds for 4 nodes x 9 types prefetched lane-spread; degS from same
//  - NODE-PER-GROUP streaming: 16-lane group g owns node w*4+g; each group
//    walks its own segment in a predicated 4-deep loop (gl covers 8 ch via
//    short8). 16 rows in flight/wave, no readlane, no vmcnt(0) drains.
//    Per record: gather short8 -> bf16 LDS RMW (b128), in-order per group.
//  - barrier; MFMA acc += Mt @ W[dir] (swapped operands); barrier.
// Epilogue: + deg_t*b_t both dirs, single fp32 out store.
__global__ __launch_bounds__(256, 4) void fused_rgcn(
    const unsigned short* __restrict__ Hbf, const unsigned short* __restrict__ Wt,
    const float* __restrict__ B18,
    const int* __restrict__ off3, const int* __restrict__ cur3,
    const unsigned* __restrict__ rec,
    float* __restrict__ out, int Nn)
{
    __shared__ __align__(16) unsigned short Mt[TN][MT_P];
    __shared__ float degS[2][TN][R_REL];

    const int tid = threadIdx.x;
    const int lane = tid & 63;
    const int w = tid >> 6;             // wave id; col slice w*32..w*32+31
    const int lr = lane & 15;
    const int lg = lane >> 4;
    const int grp = lg;                 // node-in-wave (aggregation role)
    const int gl = lr;                  // channel sub-lane: ch gl*8..gl*8+7
    const int n0 = blockIdx.x * TN;

    const short8v* wt8 = (const short8v*)Wt;
    const short8v z8 = (short8v){0, 0, 0, 0, 0, 0, 0, 0};

    f32x4 acc[2];
    acc[0] = (f32x4){0.f, 0.f, 0.f, 0.f};
    acc[1] = (f32x4){0.f, 0.f, 0.f, 0.f};

#define RMW(rk, vk)                                                           \
    {                                                                         \
        int _t = (int)((rk) >> 20);                                           \
        unsigned short* _mp = &Mt[w * 4 + grp][_t * E_DIM + gl * 8];          \
        short8v _m = *(short8v*)_mp;                                          \
        _Pragma("unroll")                                                     \
        for (int _c = 0; _c < 8; _c++) {                                      \
            float _f = bf2f((unsigned short)_m[_c]) +                         \
                       bf2f((unsigned short)(vk)[_c]);                        \
            _m[_c] = (short)f2bf(_f);                                         \
        }                                                                     \
        *(short8v*)_mp = _m;                                                  \
    }

#pragma unroll 1
    for (int dir = 0; dir < 2; dir++) {
        // Zero this wave's Mt rows (1152 used ushorts per row).
#pragma unroll
        for (int rr = 0; rr < 4; rr++) {
            int row = w * 4 + rr;
            *(short8v*)(&Mt[row][(size_t)lane * 8]) = z8;
            *(short8v*)(&Mt[row][(size_t)(lane + 64) * 8]) = z8;
            if (lane < 16) *(short8v*)(&Mt[row][(size_t)(lane + 128) * 8]) = z8;
        }

        // Prefetch bounds: lane = jj*16 + tt (jj = node-in-wave, tt = type).
        const int jj = lg, tt = lr;
        const int gnode_j = n0 + w * 4 + jj;
        int blo = 0x7F000000, bhi = 0x7F000000;
        if (gnode_j < Nn && tt < R_REL) {
            size_t sb = ((size_t)(dir ? (Nn + gnode_j) : gnode_j)) * R_REL + tt;
            blo = off3[sb];
            bhi = cur3[sb];
            degS[dir][w * 4 + jj][tt] = (float)(bhi - blo);
        }

        // Per-group record range (uniform within group).
        const int st_g = __shfl(blo, grp * 16 + 0);
        const int en_g = __shfl(bhi, grp * 16 + 8);

        int ii = st_g;
        while (__any(ii < en_g)) {
            bool a0 = ii + 0 < en_g;
            bool a1 = ii + 1 < en_g;
            bool a2 = ii + 2 < en_g;
            bool a3 = ii + 3 < en_g;
            unsigned r0 = 0, r1 = 0, r2 = 0, r3 = 0;
            if (a0) r0 = rec[ii + 0];
            if (a1) r1 = rec[ii + 1];
            if (a2) r2 = rec[ii + 2];
            if (a3) r3 = rec[ii + 3];
            short8v v0 = z8, v1 = z8, v2 = z8, v3 = z8;
            if (a0) v0 = *(const short8v*)(Hbf + (size_t)(r0 & 0xFFFFF) * E_DIM + gl * 8);
            if (a1) v1 = *(const short8v*)(Hbf + (size_t)(r1 & 0xFFFFF) * E_DIM + gl * 8);
            if (a2) v2 = *(const short8v*)(Hbf + (size_t)(r2 & 0xFFFFF) * E_DIM + gl * 8);
            if (a3) v3 = *(const short8v*)(Hbf + (size_t)(r3 & 0xFFFFF) * E_DIM + gl * 8);
            if (a0) RMW(r0, v0);
            if (a1) RMW(r1, v1);
            if (a2) RMW(r2, v2);
            if (a3) RMW(r3, v3);
            ii += 4;
        }
        __syncthreads();

        // ---- GEMM: acc += Mt @ W[dir group] ----
#pragma unroll 1
        for (int q = 0; q < R_REL; q++) {
            const int rel = dir * R_REL + q;
#pragma unroll
            for (int s = 0; s < 4; s++) {
                short8v b0 = wt8[(size_t)((((rel * 4 + w) * 4 + s) * 2 + 0) * 64) + lane];
                short8v b1 = wt8[(size_t)((((rel * 4 + w) * 4 + s) * 2 + 1) * 64) + lane];
                short8v a = *(const short8v*)(&Mt[lr][q * E_DIM + s * 32 + lg * 8]);
                acc[0] = __builtin_amdgcn_mfma_f32_16x16x32_bf16(b0, a, acc[0], 0, 0, 0);
                acc[1] = __builtin_amdgcn_mfma_f32_16x16x32_bf16(b1, a, acc[1], 0, 0, 0);
            }
        }
        __syncthreads();   // before next dir overwrites Mt
    }
#undef RMW

    // ---- epilogue: bias (deg_t * b_t) + store ----
    const int gnode = n0 + lr;
    if (gnode >= Nn) return;
#pragma unroll 1
    for (int dir = 0; dir < 2; dir++) {
#pragma unroll 1
        for (int t = 0; t < R_REL; t++) {
            float dg = degS[dir][lr][t];
            if (dg != 0.f) {
                const float* brow = B18 + (size_t)(dir * R_REL + t) * E_DIM + w * 32 + lg * 4;
                float4 b0 = *(const float4*)(brow);
                float4 b1 = *(const float4*)(brow + 16);
                acc[0][0] += dg * b0.x; acc[0][1] += dg * b0.y;
                acc[0][2] += dg * b0.z; acc[0][3] += dg * b0.w;
                acc[1][0] += dg * b1.x; acc[1][1] += dg * b1.y;
                acc[1][2] += dg * b1.z; acc[1][3] += dg * b1.w;
            }
        }
    }
    float* po = out + (size_t)gnode * E_DIM + w * 32 + lg * 4;
    *(float4*)po = make_float4(acc[0][0], acc[0][1], acc[0][2], acc[0][3]);
    *(float4*)(po + 16) = make_float4(acc[1][0], acc[1][1], acc[1][2], acc[1][3]);
}

// ---------- zero-workspace fallback (round-1, validated) ----------

__global__ __launch_bounds__(128) void direct_edge(
    const int* __restrict__ esrc, const int* __restrict__ edst,
    const int* __restrict__ etype,
    const float* __restrict__ H, const float* __restrict__ W2,
    const float* __restrict__ B2, float* __restrict__ out, int ne)
{
    __shared__ float hs[E_DIM];
    __shared__ float hd[E_DIM];
    int e = blockIdx.x;
    if (e >= ne) return;
    int t = etype[e], s = esrc[e], d = edst[e];
    int c = threadIdx.x;
    hs[c] = H[(size_t)s * E_DIM + c];
    hd[c] = H[(size_t)d * E_DIM + c];
    __syncthreads();
    const float* Wf = W2 + (size_t)t * E_DIM * E_DIM;
    const float* Wb = W2 + (size_t)(t + R_REL) * E_DIM * E_DIM;
    float accf = B2[(size_t)t * E_DIM + c];
    float accb = B2[(size_t)(t + R_REL) * E_DIM + c];
#pragma unroll 8
    for (int k = 0; k < E_DIM; k++) {
        accf += hs[k] * Wf[(size_t)k * E_DIM + c];
        accb += hd[k] * Wb[(size_t)k * E_DIM + c];
    }
    atomicAdd(&out[(size_t)d * E_DIM + c], accf);
    atomicAdd(&out[(size_t)s * E_DIM + c], accb);
}

extern "C" void kernel_launch(void* const* d_in, const int* in_sizes, int n_in,
                              void* d_out, int out_size, void* d_ws, size_t ws_size,
                              hipStream_t stream) {
    const int* edge_index = (const int*)d_in[0];   // [2][NE]
    const int* edge_type  = (const int*)d_in[1];   // [NE]
    const float* emb      = (const float*)d_in[2]; // [N][128]
    const float* weights  = (const float*)d_in[3]; // [L][18][128][128]
    const float* biases   = (const float*)d_in[4]; // [L][18][128]
    float* out = (float*)d_out;

    const int NE = in_sizes[1];
    const int Nn = in_sizes[2] / E_DIM;
    const int L  = in_sizes[3] / (2 * R_REL * E_DIM * E_DIM);

    const float* W2 = weights + (size_t)(L - 1) * 2 * R_REL * E_DIM * E_DIM;
    const float* B2 = biases  + (size_t)(L - 1) * 2 * R_REL * E_DIM;

    const int* esrc = edge_index;
    const int* edst = edge_index + NE;

    const int n3 = 2 * Nn * R_REL;                 // (node,dir,type) segments
    const int nb3 = (n3 + SCB - 1) / SCB;

    auto al = [](size_t x) { return (x + 255) & ~(size_t)255; };
    const size_t hbfBytes = al((size_t)Nn * E_DIM * 2);
    const size_t wtBytes  = al((size_t)2 * R_REL * E_DIM * E_DIM * 2);
    const size_t offBytes = al((size_t)n3 * 4);
    const size_t curBytes = al((size_t)n3 * 4);
    const size_t recBytes = al((size_t)2 * NE * 4);
    const size_t bsBytes  = al((size_t)nb3 * 4);
    const size_t need = hbfBytes + wtBytes + offBytes + curBytes + recBytes + bsBytes;

    if (ws_size >= need && Nn < (1 << 20)) {
        char* p = (char*)d_ws;
        unsigned short* Hbf = (unsigned short*)p;        p += hbfBytes;
        unsigned short* Wt  = (unsigned short*)p;        p += wtBytes;
        int* off3           = (int*)p;                   p += offBytes;
        int* cur3           = (int*)p;                   p += curBytes;
        unsigned* rec       = (unsigned*)p;              p += recBytes;
        int* bsum           = (int*)p;

        const long total8 = (long)Nn * (E_DIM / 8);
        const int hblocks = (int)((total8 + 255) / 256);

        hipMemsetAsync(off3, 0, (size_t)n3 * 4, stream);
        prep<<<18 + hblocks, 256, 0, stream>>>(emb, W2, Hbf, Wt, total8);
        k_count8<<<8 * NSLICE, 256, 0, stream>>>(esrc, edst, edge_type, off3, NE, Nn);
        k_scan_part<<<nb3, 256, 0, stream>>>(off3, cur3, bsum, n3);
        k_scan_mid<<<1, 256, 0, stream>>>(bsum, nb3);
        k_scan_apply<<<nb3, 256, 0, stream>>>(cur3, bsum, off3, cur3, n3);
        k_fill8<<<8 * NSLICE, 256, 0, stream>>>(esrc, edst, edge_type,
                                                cur3, rec, NE, Nn);

        fused_rgcn<<<(Nn + TN - 1) / TN, 256, 0, stream>>>(
            Hbf, Wt, B2, off3, cur3, rec, out, Nn);
        return;
    }

    // Fallback: direct per-edge GEMV with atomics.
    hipMemsetAsync(d_out, 0, (size_t)Nn * E_DIM * sizeof(float), stream);
    direct_edge<<<NE, 128, 0, stream>>>(esrc, edst, edge_type, emb, W2, B2, out, NE);
}

// Round 14
// 348.451 us; speedup vs baseline: 1.1900x; 1.1900x over previous
//
#include <hip/hip_runtime.h>
#include <hip/hip_bf16.h>

// RGCN encoder: N=100000, E=128, R=9, L=3, NE=640000. Only the LAST layer
// matters (reference resets hidden=embeddings each layer).
//   out[n] = sum_{e:dst=n}(W_t h[src]+b_t) + sum_{e:src=n}(W_{t+9} h[dst]+b_{t+9})
// AGGREGATE-FIRST (linearity): out[d] = sum_t W_t * M_t[d] + deg_t(d)*b_t.
// Round-14: empirical law from r8 vs r12/r13 -- random-gather request
// throughput scales with OCCUPANCY (1.82 TB/s @70% vs 1.18 @42%). r13's
// 38.4KB LDS capped us at 4 blocks/CU. Fix: split K into 3 type-chunks
// (types 0-2 / 3-5 / 6-8); per chunk aggregate->MFMA into the persistent
// accumulator; Mt shrinks to 16x392 -> LDS 13.7KB -> 8 blocks/CU =
// 32 waves = 100% occupancy. Gather volume, RMW, CSR, epilogue unchanged.

#define E_DIM 128
#define R_REL 9
#define TN 16        // nodes per fused block
#define TCH 3        // types per chunk
#define MT_P2 392    // Mt pitch in ushorts (384 used + 8 pad; 784B, 16B-aligned)
#define SCB 1024     // elements per scan block
#define NSLICE 96    // edge slices per octant in count/fill

typedef __attribute__((ext_vector_type(8))) short short8v;
typedef __attribute__((ext_vector_type(4))) float f32x4;

static __device__ __forceinline__ unsigned short f2bf(float f) {
    union { float f; unsigned u; } v; v.f = f;
    unsigned u = v.u;
    return (unsigned short)((u + 0x7FFFu + ((u >> 16) & 1u)) >> 16);
}
static __device__ __forceinline__ float bf2f(unsigned short h) {
    union { unsigned u; float f; } v; v.u = ((unsigned)h) << 16;
    return v.f;
}

// ---------- fast path ----------

// Combined prep: blocks 0..17 swizzle W into MFMA fragment order; blocks 18..
// convert H fp32 -> bf16.
__global__ __launch_bounds__(256) void prep(
    const float* __restrict__ H, const float* __restrict__ W18,
    unsigned short* __restrict__ Hbf, unsigned short* __restrict__ Wt,
    long total8)
{
    const int tid = threadIdx.x;
    if (blockIdx.x < 18) {
        const int rel = blockIdx.x;
        const float* __restrict__ Wr = W18 + (size_t)rel * E_DIM * E_DIM;
#pragma unroll
        for (int k = 0; k < 8; k++) {
            int f = tid + k * 256;            // 0..2047
            int lane = f & 63;
            int c = (f >> 6) & 1;
            int s = (f >> 7) & 3;
            int w = (f >> 9) & 3;
            int col = w * 32 + c * 16 + (lane & 15);
            int kb = s * 32 + (lane >> 4) * 8;
            short8v v;
#pragma unroll
            for (int j = 0; j < 8; j++)
                v[j] = (short)f2bf(Wr[(size_t)(kb + j) * E_DIM + col]);
            *(short8v*)(Wt + ((size_t)((((rel * 4 + w) * 4 + s) * 2 + c) * 64 + lane)) * 8) = v;
        }
    } else {
        long i = (long)(blockIdx.x - 18) * 256 + tid;
        if (i >= total8) return;
        const float4* src = (const float4*)(H + i * 8);
        float4 a = src[0], b = src[1];
        short8v o;
        o[0] = (short)f2bf(a.x); o[1] = (short)f2bf(a.y);
        o[2] = (short)f2bf(a.z); o[3] = (short)f2bf(a.w);
        o[4] = (short)f2bf(b.x); o[5] = (short)f2bf(b.y);
        o[6] = (short)f2bf(b.z); o[7] = (short)f2bf(b.w);
        *(short8v*)(Hbf + i * 8) = o;
    }
}

// CSR over n3 = 2*Nn*9 (node,dir,type) segments; key = seg*9+t, seg = d (fwd)
// or Nn+s (bwd). Octant-partitioned by node: counter window L2-local.
__global__ __launch_bounds__(256) void k_count8(
    const int* __restrict__ esrc, const int* __restrict__ edst,
    const int* __restrict__ etype, int* __restrict__ cnt, int ne, int Nn)
{
    const int oct = blockIdx.x & 7;
    const int slice = blockIdx.x >> 3;
    const int lo = (int)(((long long)oct * Nn) >> 3);
    const int hi = (int)(((long long)(oct + 1) * Nn) >> 3);
    for (int e = slice * 256 + threadIdx.x; e < ne; e += NSLICE * 256) {
        int t = etype[e], s = esrc[e], d = edst[e];
        if (d >= lo && d < hi) atomicAdd(&cnt[d * R_REL + t], 1);
        if (s >= lo && s < hi) atomicAdd(&cnt[(Nn + s) * R_REL + t], 1);
    }
}

// Hierarchical scan, 3 kernels (r5-validated).
__global__ __launch_bounds__(256) void k_scan_part(
    const int* __restrict__ cnt, int* __restrict__ loc,
    int* __restrict__ bsum, int n2)
{
    __shared__ int sh[256];
    const int tid = threadIdx.x;
    const int i0 = blockIdx.x * SCB + tid * 4;
    int v0 = 0, v1 = 0, v2 = 0, v3 = 0;
    if (i0 + 3 < n2) {
        int4 v = *(const int4*)(cnt + i0);
        v0 = v.x; v1 = v.y; v2 = v.z; v3 = v.w;
    } else {
        if (i0 + 0 < n2) v0 = cnt[i0 + 0];
        if (i0 + 1 < n2) v1 = cnt[i0 + 1];
        if (i0 + 2 < n2) v2 = cnt[i0 + 2];
        if (i0 + 3 < n2) v3 = cnt[i0 + 3];
    }
    int t = v0 + v1 + v2 + v3;
    sh[tid] = t;
    __syncthreads();
    for (int o = 1; o < 256; o <<= 1) {
        int x = (tid >= o) ? sh[tid - o] : 0;
        __syncthreads();
        sh[tid] += x;
        __syncthreads();
    }
    int excl = sh[tid] - t;
    if (tid == 255) bsum[blockIdx.x] = sh[255];
    int p0 = excl, p1 = p0 + v0, p2 = p1 + v1, p3 = p2 + v2;
    if (i0 + 3 < n2) {
        *(int4*)(loc + i0) = make_int4(p0, p1, p2, p3);
    } else {
        if (i0 + 0 < n2) loc[i0 + 0] = p0;
        if (i0 + 1 < n2) loc[i0 + 1] = p1;
        if (i0 + 2 < n2) loc[i0 + 2] = p2;
        if (i0 + 3 < n2) loc[i0 + 3] = p3;
    }
}

__global__ __launch_bounds__(256) void k_scan_mid(int* __restrict__ bsum, int nb)
{
    __shared__ int sh[256];
    __shared__ int carry;
    const int tid = threadIdx.x;
    if (tid == 0) carry = 0;
    __syncthreads();
    for (int base = 0; base < nb; base += 256) {
        int i = base + tid;
        int v = (i < nb) ? bsum[i] : 0;
        sh[tid] = v;
        __syncthreads();
        for (int o = 1; o < 256; o <<= 1) {
            int x = (tid >= o) ? sh[tid - o] : 0;
            __syncthreads();
            sh[tid] += x;
            __syncthreads();
        }
        int excl = sh[tid] - v + carry;
        int total = sh[255];
        if (i < nb) bsum[i] = excl;
        __syncthreads();
        if (tid == 0) carry += total;
        __syncthreads();
    }
}

__global__ __launch_bounds__(256) void k_scan_apply(
    const int* __restrict__ loc, const int* __restrict__ bsum,
    int* __restrict__ off, int* __restrict__ cursor, int n2)
{
    const int add = bsum[blockIdx.x];
    const int i0 = blockIdx.x * SCB + threadIdx.x * 4;
    if (i0 + 3 < n2) {
        int4 v = *(const int4*)(loc + i0);
        v.x += add; v.y += add; v.z += add; v.w += add;
        *(int4*)(off + i0) = v;
        *(int4*)(cursor + i0) = v;
    } else {
#pragma unroll
        for (int j = 0; j < 4; j++)
            if (i0 + j < n2) {
                int v = loc[i0 + j] + add;
                off[i0 + j] = v;
                cursor[i0 + j] = v;
            }
    }
}

// rec = (t<<20) | otherNode, via (node,t) cursor -> type-grouped per node.
__global__ __launch_bounds__(256) void k_fill8(
    const int* __restrict__ esrc, const int* __restrict__ edst,
    const int* __restrict__ etype, int* __restrict__ cursor,
    unsigned* __restrict__ rec, int ne, int Nn)
{
    const int oct = blockIdx.x & 7;
    const int slice = blockIdx.x >> 3;
    const int lo = (int)(((long long)oct * Nn) >> 3);
    const int hi = (int)(((long long)(oct + 1) * Nn) >> 3);
    for (int e = slice * 256 + threadIdx.x; e < ne; e += NSLICE * 256) {
        int t = etype[e], s = esrc[e], d = edst[e];
        if (d >= lo && d < hi) {
            int p = atomicAdd(&cursor[d * R_REL + t], 1);
            rec[p] = ((unsigned)t << 20) | (unsigned)s;   // fwd msg into d
        }
        if (s >= lo && s < hi) {
            int p2 = atomicAdd(&cursor[(Nn + s) * R_REL + t], 1);
            rec[p2] = ((unsigned)t << 20) | (unsigned)d;  // bwd msg into s
        }
    }
}

// Fused aggregate+GEMM, K split in 3 type-chunks for occupancy.
// Block = 16 nodes, 4 waves, LDS ~13.7KB -> 8 blocks/CU = 32 waves (100%).
// Per dir: prefetch all 9 type-bounds (lane-spread) + degS; per chunk c:
//   zero Mt[16][384]; group g streams node w*4+g's records of types
//   [3c,3c+3) (4-deep predicated, short8/lane); bf16 LDS RMW; barrier;
//   MFMA acc += Mt_chunk @ W[dir,chunk] (swapped operands); barrier.
// Epilogue: + deg_t*b_t both dirs, single fp32 out store.
__global__ __launch_bounds__(256, 8) void fused_rgcn(
    const unsigned short* __restrict__ Hbf, const unsigned short* __restrict__ Wt,
    const float* __restrict__ B18,
    const int* __restrict__ off3, const int* __restrict__ cur3,
    const unsigned* __restrict__ rec,
    float* __restrict__ out, int Nn)
{
    __shared__ __align__(16) unsigned short Mt[TN][MT_P2];
    __shared__ float degS[2][TN][R_REL];

    const int tid = threadIdx.x;
    const int lane = tid & 63;
    const int w = tid >> 6;             // wave id; col slice w*32..w*32+31
    const int lr = lane & 15;
    const int lg = lane >> 4;
    const int grp = lg;                 // node-in-wave (aggregation role)
    const int gl = lr;                  // channel sub-lane: ch gl*8..gl*8+7
    const int n0 = blockIdx.x * TN;

    const short8v* wt8 = (const short8v*)Wt;
    const short8v z8 = (short8v){0, 0, 0, 0, 0, 0, 0, 0};

    f32x4 acc[2];
    acc[0] = (f32x4){0.f, 0.f, 0.f, 0.f};
    acc[1] = (f32x4){0.f, 0.f, 0.f, 0.f};

#define RMW(rk, vk, tbase)                                                    \
    {                                                                         \
        int _tl = (int)((rk) >> 20) - (tbase);                                \
        unsigned short* _mp = &Mt[w * 4 + grp][_tl * E_DIM + gl * 8];         \
        short8v _m = *(short8v*)_mp;                                          \
        _Pragma("unroll")                                                     \
        for (int _c = 0; _c < 8; _c++) {                                      \
            float _f = bf2f((unsigned short)_m[_c]) +                         \
                       bf2f((unsigned short)(vk)[_c]);                        \
            _m[_c] = (short)f2bf(_f);                                        \
        }                                                                     \
        *(short8v*)_mp = _m;                                                  \
    }

#pragma unroll 1
    for (int dir = 0; dir < 2; dir++) {
        // Prefetch bounds: lane = jj*16 + tt (jj = node-in-wave, tt = type).
        const int jj = lg, tt = lr;
        const int gnode_j = n0 + w * 4 + jj;
        int blo = 0x7F000000, bhi = 0x7F000000;
        if (gnode_j < Nn && tt < R_REL) {
            size_t sb = ((size_t)(dir ? (Nn + gnode_j) : gnode_j)) * R_REL + tt;
            blo = off3[sb];
            bhi = cur3[sb];
            degS[dir][w * 4 + jj][tt] = (float)(bhi - blo);
        }

#pragma unroll 1
        for (int ch = 0; ch < 3; ch++) {
            const int tbase = ch * TCH;
            // Zero this wave's Mt rows (384 used ushorts = 48 short8/row).
#pragma unroll
            for (int rr = 0; rr < 4; rr++) {
                if (lane < 48)
                    *(short8v*)(&Mt[w * 4 + rr][(size_t)lane * 8]) = z8;
            }

            // Per-group record range for this chunk (types tbase..tbase+2).
            const int st_g = __shfl(blo, grp * 16 + tbase);
            const int en_g = __shfl(bhi, grp * 16 + tbase + TCH - 1);

            int ii = st_g;
            while (__any(ii < en_g)) {
                bool a0 = ii + 0 < en_g;
                bool a1 = ii + 1 < en_g;
                bool a2 = ii + 2 < en_g;
                bool a3 = ii + 3 < en_g;
                unsigned r0 = 0, r1 = 0, r2 = 0, r3 = 0;
                if (a0) r0 = rec[ii + 0];
                if (a1) r1 = rec[ii + 1];
                if (a2) r2 = rec[ii + 2];
                if (a3) r3 = rec[ii + 3];
                short8v v0 = z8, v1 = z8, v2 = z8, v3 = z8;
                if (a0) v0 = *(const short8v*)(Hbf + (size_t)(r0 & 0xFFFFF) * E_DIM + gl * 8);
                if (a1) v1 = *(const short8v*)(Hbf + (size_t)(r1 & 0xFFFFF) * E_DIM + gl * 8);
                if (a2) v2 = *(const short8v*)(Hbf + (size_t)(r2 & 0xFFFFF) * E_DIM + gl * 8);
                if (a3) v3 = *(const short8v*)(Hbf + (size_t)(r3 & 0xFFFFF) * E_DIM + gl * 8);
                if (a0) RMW(r0, v0, tbase);
                if (a1) RMW(r1, v1, tbase);
                if (a2) RMW(r2, v2, tbase);
                if (a3) RMW(r3, v3, tbase);
                ii += 4;
            }
            __syncthreads();

            // ---- GEMM: acc += Mt_chunk @ W[dir, chunk types] ----
#pragma unroll
            for (int q = 0; q < TCH; q++) {
                const int rel = dir * R_REL + tbase + q;
#pragma unroll
                for (int s = 0; s < 4; s++) {
                    short8v b0 = wt8[(size_t)((((rel * 4 + w) * 4 + s) * 2 + 0) * 64) + lane];
                    short8v b1 = wt8[(size_t)((((rel * 4 + w) * 4 + s) * 2 + 1) * 64) + lane];
                    short8v a = *(const short8v*)(&Mt[lr][q * E_DIM + s * 32 + lg * 8]);
                    acc[0] = __builtin_amdgcn_mfma_f32_16x16x32_bf16(b0, a, acc[0], 0, 0, 0);
                    acc[1] = __builtin_amdgcn_mfma_f32_16x16x32_bf16(b1, a, acc[1], 0, 0, 0);
                }
            }
            __syncthreads();   // before next chunk overwrites Mt
        }
    }
#undef RMW

    // ---- epilogue: bias (deg_t * b_t) + store ----
    const int gnode = n0 + lr;
    if (gnode >= Nn) return;
#pragma unroll 1
    for (int dir = 0; dir < 2; dir++) {
#pragma unroll 1
        for (int t = 0; t < R_REL; t++) {
            float dg = degS[dir][lr][t];
            if (dg != 0.f) {
                const float* brow = B18 + (size_t)(dir * R_REL + t) * E_DIM + w * 32 + lg * 4;
                float4 b0 = *(const float4*)(brow);
                float4 b1 = *(const float4*)(brow + 16);
                acc[0][0] += dg * b0.x; acc[0][1] += dg * b0.y;
                acc[0][2] += dg * b0.z; acc[0][3] += dg * b0.w;
                acc[1][0] += dg * b1.x; acc[1][1] += dg * b1.y;
                acc[1][2] += dg * b1.z; acc[1][3] += dg * b1.w;
            }
        }
    }
    float* po = out + (size_t)gnode * E_DIM + w * 32 + lg * 4;
    *(float4*)po = make_float4(acc[0][0], acc[0][1], acc[0][2], acc[0][3]);
    *(float4*)(po + 16) = make_float4(acc[1][0], acc[1][1], acc[1][2], acc[1][3]);
}

// ---------- zero-workspace fallback (round-1, validated) ----------

__global__ __launch_bounds__(128) void direct_edge(
    const int* __restrict__ esrc, const int* __restrict__ edst,
    const int* __restrict__ etype,
    const float* __restrict__ H, const float* __restrict__ W2,
    const float* __restrict__ B2, float* __restrict__ out, int ne)
{
    __shared__ float hs[E_DIM];
    __shared__ float hd[E_DIM];
    int e = blockIdx.x;
    if (e >= ne) return;
    int t = etype[e], s = esrc[e], d = edst[e];
    int c = threadIdx.x;
    hs[c] = H[(size_t)s * E_DIM + c];
    hd[c] = H[(size_t)d * E_DIM + c];
    __syncthreads();
    const float* Wf = W2 + (size_t)t * E_DIM * E_DIM;
    const float* Wb = W2 + (size_t)(t + R_REL) * E_DIM * E_DIM;
    float accf = B2[(size_t)t * E_DIM + c];
    float accb = B2[(size_t)(t + R_REL) * E_DIM + c];
#pragma unroll 8
    for (int k = 0; k < E_DIM; k++) {
        accf += hs[k] * Wf[(size_t)k * E_DIM + c];
        accb += hd[k] * Wb[(size_t)k * E_DIM + c];
    }
    atomicAdd(&out[(size_t)d * E_DIM + c], accf);
    atomicAdd(&out[(size_t)s * E_DIM + c], accb);
}

extern "C" void kernel_launch(void* const* d_in, const int* in_sizes, int n_in,
                              void* d_out, int out_size, void* d_ws, size_t ws_size,
                              hipStream_t stream) {
    const int* edge_index = (const int*)d_in[0];   // [2][NE]
    const int* edge_type  = (const int*)d_in[1];   // [NE]
    const float* emb      = (const float*)d_in[2]; // [N][128]
    const float* weights  = (const float*)d_in[3]; // [L][18][128][128]
    const float* biases   = (const float*)d_in[4]; // [L][18][128]
    float* out = (float*)d_out;

    const int NE = in_sizes[1];
    const int Nn = in_sizes[2] / E_DIM;
    const int L  = in_sizes[3] / (2 * R_REL * E_DIM * E_DIM);

    const float* W2 = weights + (size_t)(L - 1) * 2 * R_REL * E_DIM * E_DIM;
    const float* B2 = biases  + (size_t)(L - 1) * 2 * R_REL * E_DIM;

    const int* esrc = edge_index;
    const int* edst = edge_index + NE;

    const int n3 = 2 * Nn * R_REL;                 // (node,dir,type) segments
    const int nb3 = (n3 + SCB - 1) / SCB;

    auto al = [](size_t x) { return (x + 255) & ~(size_t)255; };
    const size_t hbfBytes = al((size_t)Nn * E_DIM * 2);
    const size_t wtBytes  = al((size_t)2 * R_REL * E_DIM * E_DIM * 2);
    const size_t offBytes = al((size_t)n3 * 4);
    const size_t curBytes = al((size_t)n3 * 4);
    const size_t recBytes = al((size_t)2 * NE * 4);
    const size_t bsBytes  = al((size_t)nb3 * 4);
    const size_t need = hbfBytes + wtBytes + offBytes + curBytes + recBytes + bsBytes;

    if (ws_size >= need && Nn < (1 << 20)) {
        char* p = (char*)d_ws;
        unsigned short* Hbf = (unsigned short*)p;        p += hbfBytes;
        unsigned short* Wt  = (unsigned short*)p;        p += wtBytes;
        int* off3           = (int*)p;                   p += offBytes;
        int* cur3           = (int*)p;                   p += curBytes;
        unsigned* rec       = (unsigned*)p;              p += recBytes;
        int* bsum           = (int*)p;

        const long total8 = (long)Nn * (E_DIM / 8);
        const int hblocks = (int)((total8 + 255) / 256);

        hipMemsetAsync(off3, 0, (size_t)n3 * 4, stream);
        prep<<<18 + hblocks, 256, 0, stream>>>(emb, W2, Hbf, Wt, total8);
        k_count8<<<8 * NSLICE, 256, 0, stream>>>(esrc, edst, edge_type, off3, NE, Nn);
        k_scan_part<<<nb3, 256, 0, stream>>>(off3, cur3, bsum, n3);
        k_scan_mid<<<1, 256, 0, stream>>>(bsum, nb3);
        k_scan_apply<<<nb3, 256, 0, stream>>>(cur3, bsum, off3, cur3, n3);
        k_fill8<<<8 * NSLICE, 256, 0, stream>>>(esrc, edst, edge_type,
                                                cur3, rec, NE, Nn);

        fused_rgcn<<<(Nn + TN - 1) / TN, 256, 0, stream>>>(
            Hbf, Wt, B2, off3, cur3, rec, out, Nn);
        return;
    }

    // Fallback: direct per-edge GEMV with atomics.
    hipMemsetAsync(d_out, 0, (size_t)Nn * E_DIM * sizeof(float), stream);
    direct_edge<<<NE, 128, 0, stream>>>(esrc, edst, edge_type, emb, W2, B2, out, NE);
}